// Round 10
// baseline (26.826 us; speedup 1.0000x reference)
//
#include <hip/hip_runtime.h>
#include <hip/hip_bf16.h>

#define TT 1024
#define AA 16
#define DTS 0.4f
#define EPSV 1e-6f

typedef float f4 __attribute__((ext_vector_type(4)));

// dd components (x,y) of (ado-ado_wo)'' for flat row `row` at time t; 0 at ends
__device__ __forceinline__ float2 dd2(const float2* __restrict__ A,
                                      const float2* __restrict__ B,
                                      int row, int t) {
    if (t <= 0 || t >= TT - 1) return make_float2(0.f, 0.f);
    const float2* a = A + row * TT + t;
    const float2* b = B + row * TT + t;
    float2 am = a[-1], a0 = a[0], ap = a[1];
    float2 bm = b[-1], b0 = b[0], bp = b[1];
    const float s = 1.0f / (DTS * DTS);
    float2 r;
    r.x = ((am.x - bm.x) - 2.f * (a0.x - b0.x) + (ap.x - bp.x)) * s;
    r.y = ((am.y - bm.y) - 2.f * (a0.y - b0.y) + (ap.y - bp.y)) * s;
    return r;
}

// v2: 256 blocks x 1024 threads (16 waves/CU). Block = (j, 64-t chunk).
// Wave sub = tid>>6 in [0,16) is BOTH the a-index (w-term) and m-index (s-term):
// each thread does 2 dd2 (+2 boundary) instead of 32 -> short latency chains.
// Block 0 also zeroes out[0..2047] (stream-ordered before grad's atomics).
__global__ __launch_bounds__(1024) void wscoef_kernel(const float* __restrict__ ado,
                                                      const float* __restrict__ ado_wo,
                                                      float* __restrict__ ws,
                                                      float* __restrict__ coef,
                                                      float* __restrict__ out) {
    const int bid = blockIdx.x;
    const int tid = threadIdx.x;
    if (bid == 0) { out[tid] = 0.0f; out[tid + 1024] = 0.0f; }

    const int j = bid >> 4;
    const int chunk = bid & 15;
    const int sub = tid >> 6;      // a-index / m-index
    const int lane = tid & 63;
    const int t = chunk * 64 + lane;
    const int tb = chunk * 64 + 64;     // boundary t (next chunk's first slice)
    const float2* A = (const float2*)ado;
    const float2* B = (const float2*)ado_wo;

    // w partial: a = sub, row = a*AA + j
    float2 d = dd2(A, B, sub * AA + j, t);
    float n = sqrtf(d.x * d.x + d.y * d.y);
    float w = (n < EPSV) ? 0.f : 1.f / n;
    // s partial: m = sub, row = j*AA + m
    float2 e = dd2(A, B, j * AA + sub, t);

    float wb = 0.f, sbx = 0.f, sby = 0.f;
    if (tb < TT) {   // uniform across lanes (broadcast loads)
        float2 db = dd2(A, B, sub * AA + j, tb);
        float nb = sqrtf(db.x * db.x + db.y * db.y);
        wb = (nb < EPSV) ? 0.f : 1.f / nb;
        float2 eb = dd2(A, B, j * AA + sub, tb);
        sbx = eb.x; sby = eb.y;
    }

    __shared__ float lw[16][64], lsx[16][64], lsy[16][64];
    __shared__ float lwb[16], lsbx[16], lsby[16];
    lw[sub][lane] = w; lsx[sub][lane] = e.x; lsy[sub][lane] = e.y;
    if (lane == 0) { lwb[sub] = wb; lsbx[sub] = sbx; lsby[sub] = sby; }
    __syncthreads();

    if (tid < 64) {
        float W = 0.f, SX = 0.f, SY = 0.f, WB = 0.f, BX = 0.f, BY = 0.f;
        #pragma unroll
        for (int i = 0; i < 16; ++i) {
            W += lw[i][tid]; SX += lsx[i][tid]; SY += lsy[i][tid];
            WB += lwb[i];    BX += lsbx[i];     BY += lsby[i];
        }
        float wsx = W * SX, wsy = W * SY;
        float wbx = WB * BX, wby = WB * BY;

        int tt = chunk * 64 + tid;
        *(float2*)(ws + tt * 32 + j * 2) = make_float2(wsx, wsy);

        float nx = __shfl_down(wsx, 1, 64);
        float ny = __shfl_down(wsy, 1, 64);
        if (tid == 63) { nx = wbx; ny = wby; }
        float cx = nx - 2.f * wsx;
        float cy = ny - 2.f * wsy;
        if (tt == TT - 1) { cx = 0.f; cy = 0.f; }  // coef[T-1] = 0 (unused)
        *(float2*)(coef + tt * 32 + j * 2) = make_float2(cx, cy);
    }
}

// Coefficient of pg[k,u,j,c] in out[2k+c]:
//   coef[u,j,c]  for u >= k-1   (coef[T-1] = 0 covers u = T-1)
//   ws[k-1,j,c]  for u == k-2
//   0 otherwise; k = 0 excluded entirely.
// Grid (cy=16 u-chunks of 512 f4, kt=128 k-tiles of 8 rows); early-exit below
// diagonal. Fast path: coef f4 held in register across the 8-row unroll
// (coef port traffic / 8). Masked path only on 1-2 diagonal chunks per tile.
__global__ __launch_bounds__(256, 2) void grad_kernel(const float* __restrict__ pg,
                                                      const float* __restrict__ ws,
                                                      const float* __restrict__ coef,
                                                      float* __restrict__ out) {
    const int cy = blockIdx.x;        // 0..15
    const int k0 = blockIdx.y * 8;    // 0..1016
    const int U0 = cy * 64;           // chunk u-range [U0, U0+64)
    if (U0 + 65 < k0) return;         // u_max < k0-2: nothing to do

    const int tid = threadIdx.x;
    const f4* __restrict__ pg4 = (const f4*)pg;
    const f4* __restrict__ coef4 = (const f4*)coef;
    const f4* __restrict__ ws4 = (const f4*)ws;

    float ax[8], ay[8];
    #pragma unroll
    for (int r = 0; r < 8; ++r) { ax[r] = 0.f; ay[r] = 0.f; }

    const int qbase = cy * 512;

    if (U0 >= k0 + 6) {
        // fast: every row unmasked for every u in chunk
        #pragma unroll
        for (int i = 0; i < 2; ++i) {
            const int q = qbase + i * 256 + tid;
            f4 c = coef4[q];
            f4 p[8];
            #pragma unroll
            for (int r = 0; r < 8; ++r)
                p[r] = pg4[(size_t)(k0 + r) * 8192 + q];
            #pragma unroll
            for (int r = 0; r < 8; ++r) {
                ax[r] += p[r].x * c.x + p[r].z * c.z;
                ay[r] += p[r].y * c.y + p[r].w * c.w;
            }
        }
    } else {
        // masked (diagonal) path
        #pragma unroll
        for (int i = 0; i < 2; ++i) {
            const int q = qbase + i * 256 + tid;
            const int u = q >> 3;
            f4 c = coef4[q];
            f4 wsn;
            if (q + 8 < 8192) wsn = ws4[q + 8];        // ws[u+1]
            else { wsn.x = wsn.y = wsn.z = wsn.w = 0.f; }
            #pragma unroll
            for (int r = 0; r < 8; ++r) {
                const int k = k0 + r;
                if (u + 2 < k) continue;               // no contribution, skip load
                f4 p = pg4[(size_t)k * 8192 + q];
                float pcx = p.x * c.x + p.z * c.z;
                float pcy = p.y * c.y + p.w * c.w;
                float pwx = p.x * wsn.x + p.z * wsn.z;
                float pwy = p.y * wsn.y + p.w * wsn.w;
                bool vc = (u >= k - 1);
                ax[r] += vc ? pcx : pwx;               // u==k-2 slot -> ws term
                ay[r] += vc ? pcy : pwy;
            }
        }
    }

    // reduce: wave64 shuffle, then LDS across 4 waves, then 16 atomics
    #pragma unroll
    for (int off = 32; off > 0; off >>= 1) {
        #pragma unroll
        for (int r = 0; r < 8; ++r) {
            ax[r] += __shfl_down(ax[r], off, 64);
            ay[r] += __shfl_down(ay[r], off, 64);
        }
    }
    __shared__ float red[4][16];
    const int wave = tid >> 6, lane = tid & 63;
    if (lane == 0) {
        #pragma unroll
        for (int r = 0; r < 8; ++r) {
            red[wave][2 * r + 0] = ax[r];
            red[wave][2 * r + 1] = ay[r];
        }
    }
    __syncthreads();
    if (tid < 16) {
        float v = red[0][tid] + red[1][tid] + red[2][tid] + red[3][tid];
        const int r = tid >> 1, comp = tid & 1;
        const int k = k0 + r;
        if (k > 0) atomicAdd(&out[2 * k + comp], v);   // k = 0 stays 0
    }
}

extern "C" void kernel_launch(void* const* d_in, const int* in_sizes, int n_in,
                              void* d_out, int out_size, void* d_ws, size_t ws_size,
                              hipStream_t stream) {
    const float* ado    = (const float*)d_in[0];
    const float* ado_wo = (const float*)d_in[1];
    const float* pg     = (const float*)d_in[2];
    float* out  = (float*)d_out;
    float* ws   = (float*)d_ws;                    // 32768 floats = 128 KB
    float* coef = (float*)d_ws + TT * AA * 2;      // 32768 floats = 128 KB

    wscoef_kernel<<<AA * (TT / 64), 1024, 0, stream>>>(ado, ado_wo, ws, coef, out);
    grad_kernel<<<dim3(16, 128), 256, 0, stream>>>(pg, ws, coef, out);
}